// Round 3
// baseline (273.507 us; speedup 1.0000x reference)
//
#include <hip/hip_runtime.h>

// Gridding R3: two-pass binning, zero global atomics.
//   Phase 1: 1024 blocks (one per 4096-point chunk) bin point indices (u16,
//     chunk-local) into per-(batch, x-slab) buckets partitioned by chunk.
//     LDS counters give positions; each (bucket,chunk) region has one writer.
//   Phase 2: 1024 blocks (one per (batch, x-slab)) scan ONLY their bucket
//     (~5120 pts, 1.25x dup vs 16x redundant scan of R2), accumulate into a
//     64 KiB LDS sub-grid (4 x-planes), flush coalesced. Exclusive ownership:
//     every output cell written exactly once -> no memset, no global atomics.

#define NPTS   65536
#define NCHUNK 16                 // chunks per batch
#define CHSZ   4096               // points per chunk
#define NSLAB  16
#define SLABW  4
#define CCAP   448                // capacity per (bucket, chunk); mean 320, +7 sigma
#define SUBN   (SLABW * 64 * 64)  // 16384 floats = 64 KiB

__global__ __launch_bounds__(1024) void p1_bin(
    const float* __restrict__ pt,
    unsigned short* __restrict__ buck,   // [B*16 buckets][NCHUNK][CCAP]
    int* __restrict__ bcnt)              // [B*16 buckets][NCHUNK]
{
    __shared__ int cnt[NSLAB];
    if (threadIdx.x < NSLAB) cnt[threadIdx.x] = 0;
    __syncthreads();

    const int chunk = blockIdx.x;        // B*NCHUNK total
    const int b = chunk >> 4;
    const int c = chunk & 15;
    const float* p = pt + ((size_t)b * NPTS + (size_t)c * CHSZ) * 3;

    #pragma unroll
    for (int k = 0; k < CHSZ / 1024; ++k) {
        int li = k * 1024 + threadIdx.x;             // chunk-local index
        float px = p[3 * li + 0] * 32.0f;
        float py = p[3 * li + 1] * 32.0f;
        float pz = p[3 * li + 2] * 32.0f;
        if (fabsf(px) + fabsf(py) + fabsf(pz) == 0.0f) continue;  // nz_mask
        int ix = (int)floorf(px) + 32;               // 0..64
        if ((unsigned)ix > 63u) continue;            // ix==64: both x-planes OOB
        int s0 = ix >> 2;
        int pos = atomicAdd(&cnt[s0], 1);            // LDS atomic
        if (pos < CCAP)
            buck[(((size_t)(b * NSLAB + s0)) * NCHUNK + c) * CCAP + pos] =
                (unsigned short)li;
        if ((ix & 3) == 3 && ix < 63) {              // corner x+1 in next slab
            int pos1 = atomicAdd(&cnt[s0 + 1], 1);
            if (pos1 < CCAP)
                buck[(((size_t)(b * NSLAB + s0 + 1)) * NCHUNK + c) * CCAP + pos1] =
                    (unsigned short)li;
        }
    }
    __syncthreads();
    if (threadIdx.x < NSLAB)
        bcnt[(b * NSLAB + threadIdx.x) * NCHUNK + c] = min(cnt[threadIdx.x], CCAP);
}

__global__ __launch_bounds__(1024) void p2_accum(
    const float* __restrict__ pt,
    const unsigned short* __restrict__ buck,
    const int* __restrict__ bcnt,
    float* __restrict__ out)
{
    __shared__ float g[SUBN];
    const int bs = blockIdx.x;           // b*16 + s
    const int b  = bs >> 4;
    const int s  = bs & 15;
    const int x0 = s * SLABW;

    float4* g4 = (float4*)g;
    #pragma unroll
    for (int i = threadIdx.x; i < SUBN / 4; i += 1024)
        g4[i] = make_float4(0.f, 0.f, 0.f, 0.f);
    __syncthreads();

    const float* pb = pt + (size_t)b * NPTS * 3;
    const unsigned short* myb = buck + (size_t)bs * NCHUNK * CCAP;
    const int* myc = bcnt + bs * NCHUNK;

    for (int t = threadIdx.x; t < NCHUNK * CCAP; t += 1024) {
        int c   = t / CCAP;              // const divisor -> magic mul
        int pos = t - c * CCAP;
        if (pos >= myc[c]) continue;     // 64B line holds all 16 counts (L1-hot)
        int li = (int)myb[t] + c * CHSZ; // batch-local point index

        float px = pb[3 * li + 0] * 32.0f;
        float py = pb[3 * li + 1] * 32.0f;
        float pz = pb[3 * li + 2] * 32.0f;
        float lx = floorf(px), ly = floorf(py), lz = floorf(pz);
        float fx = px - lx,    fy = py - ly,    fz = pz - lz;
        int ix = (int)lx + 32, iy = (int)ly + 32, iz = (int)lz + 32;

        float wx[2] = {1.0f - fx, fx};
        float wy[2] = {1.0f - fy, fy};
        float wz[2] = {1.0f - fz, fz};

        #pragma unroll
        for (int di = 0; di < 2; ++di) {
            int xl = ix + di - x0;                 // slab-local x
            if ((unsigned)xl >= SLABW) continue;   // x in [x0,x0+3] => globally in-bounds
            #pragma unroll
            for (int dj = 0; dj < 2; ++dj) {
                int yy = iy + dj;
                if ((unsigned)yy >= 64u) continue;
                float wxy = wx[di] * wy[dj];
                int base = (xl * 64 + yy) * 64;
                #pragma unroll
                for (int dk = 0; dk < 2; ++dk) {
                    int zz = iz + dk;
                    if ((unsigned)zz >= 64u) continue;
                    atomicAdd(&g[base + zz], wxy * wz[dk]);  // ds_add_f32
                }
            }
        }
    }
    __syncthreads();

    float4* o4 = (float4*)(out + ((size_t)b * 64 + x0) * 4096);
    #pragma unroll
    for (int i = threadIdx.x; i < SUBN / 4; i += 1024)
        o4[i] = g4[i];
}

// ---- R2 fallback (exclusive-slab redundant scan), used only if ws too small.
__global__ __launch_bounds__(1024) void gridding_slab(
    const float* __restrict__ pt, float* __restrict__ out)
{
    __shared__ float lds[SUBN];
    const int blk = blockIdx.x;
    const int b   = blk >> 4;
    const int x0  = (blk & 15) * SLABW;
    float4* l4 = (float4*)lds;
    #pragma unroll
    for (int i = threadIdx.x; i < SUBN / 4; i += 1024)
        l4[i] = make_float4(0.f, 0.f, 0.f, 0.f);
    __syncthreads();
    const float* p = pt + (size_t)b * NPTS * 3;
    for (int it = 0; it < NPTS / 1024; ++it) {
        int i = it * 1024 + threadIdx.x;
        float px = p[3 * i + 0] * 32.0f;
        float py = p[3 * i + 1] * 32.0f;
        float pz = p[3 * i + 2] * 32.0f;
        if (fabsf(px) + fabsf(py) + fabsf(pz) == 0.0f) continue;
        float lx = floorf(px), ly = floorf(py), lz = floorf(pz);
        float fx = px - lx, fy = py - ly, fz = pz - lz;
        int ix = (int)lx + 32, iy = (int)ly + 32, iz = (int)lz + 32;
        float wx[2] = {1.0f - fx, fx};
        float wy[2] = {1.0f - fy, fy};
        float wz[2] = {1.0f - fz, fz};
        #pragma unroll
        for (int di = 0; di < 2; ++di) {
            int xl = (ix + di) - x0;
            if ((unsigned)xl >= SLABW) continue;
            #pragma unroll
            for (int dj = 0; dj < 2; ++dj) {
                int yy = iy + dj;
                if ((unsigned)yy >= 64u) continue;
                float wxy = wx[di] * wy[dj];
                int base = (xl * 64 + yy) * 64;
                #pragma unroll
                for (int dk = 0; dk < 2; ++dk) {
                    int zz = iz + dk;
                    if ((unsigned)zz >= 64u) continue;
                    atomicAdd(&lds[base + zz], wxy * wz[dk]);
                }
            }
        }
    }
    __syncthreads();
    float4* o4 = (float4*)(out + ((size_t)b * 64 + x0) * 4096);
    #pragma unroll
    for (int i = threadIdx.x; i < SUBN / 4; i += 1024)
        o4[i] = l4[i];
}

extern "C" void kernel_launch(void* const* d_in, const int* in_sizes, int n_in,
                              void* d_out, int out_size, void* d_ws, size_t ws_size,
                              hipStream_t stream) {
    const float* pt = (const float*)d_in[0];
    float* out = (float*)d_out;
    const int B = (in_sizes[0] / 3) / NPTS;   // 64

    const size_t buck_elems = (size_t)B * NSLAB * NCHUNK * CCAP;
    const size_t need = buck_elems * sizeof(unsigned short)
                      + (size_t)B * NSLAB * NCHUNK * sizeof(int);

    if (ws_size >= need) {
        unsigned short* buck = (unsigned short*)d_ws;
        int* bcnt = (int*)((char*)d_ws + buck_elems * sizeof(unsigned short));
        p1_bin<<<B * NCHUNK, 1024, 0, stream>>>(pt, buck, bcnt);
        p2_accum<<<B * NSLAB, 1024, 0, stream>>>(pt, buck, bcnt, out);
    } else {
        gridding_slab<<<B * NSLAB, 1024, 0, stream>>>(pt, out);
    }
}